// Round 7
// baseline (272.685 us; speedup 1.0000x reference)
//
#include <hip/hip_runtime.h>
#include <hip/hip_bf16.h>

// MHA forward: N=2, S=T=2048, E=1024, H=16, HD=64. All-bf16 MFMA pipeline.
// attn: 32x32x16 MFMA, S^T trick (P in registers), 8-wave blocks with T-split
// wave groups + exact partial combine (fixed-shift softmax => sums add).
// vT stored t-permuted so register P is directly a PV A-operand.
// LDS XOR-chunk swizzle: slot (row,p) holds chunk p ^ (row&7).
typedef __bf16 bf16x8 __attribute__((ext_vector_type(8)));
typedef __bf16 bf16x4 __attribute__((ext_vector_type(4)));
typedef float  f32x4  __attribute__((ext_vector_type(4)));
typedef float  f32x16 __attribute__((ext_vector_type(16)));

#define MFMA16(a, b, c) __builtin_amdgcn_mfma_f32_16x16x32_bf16((a), (b), (c), 0, 0, 0)
#define MFMA32(a, b, c) __builtin_amdgcn_mfma_f32_32x32x16_bf16((a), (b), (c), 0, 0, 0)

constexpr int SEQ = 2048, EMB = 1024, NHEAD = 16, HD = 64;
constexpr float SSCALE = 0.18033688f;  // (1/8) * log2(e)

__device__ __forceinline__ void glds16(const void* g, void* l) {
    __builtin_amdgcn_global_load_lds(
        (const __attribute__((address_space(1))) void*)g,
        (__attribute__((address_space(3))) void*)l, 16, 0, 0);
}

// ---------------------------------------------------------------------------
// prep: z<4 -> weight transpose+cast (z==0 pre-scaled by SSCALE);
//       z>=4 -> fp32->bf16 convert of query/key/value.
// ---------------------------------------------------------------------------
__global__ __launch_bounds__(256)
void prep(const float* __restrict__ W0, const float* __restrict__ W1,
          const float* __restrict__ W2, const float* __restrict__ W3,
          __bf16* __restrict__ T0, __bf16* __restrict__ T1,
          __bf16* __restrict__ T2, __bf16* __restrict__ T3,
          const float* __restrict__ X0, const float* __restrict__ X1,
          const float* __restrict__ X2, __bf16* __restrict__ Y0,
          __bf16* __restrict__ Y1, __bf16* __restrict__ Y2)
{
    __shared__ float tile[32][33];
    const int z = blockIdx.z;
    if (z < 4) {
        const float* W = (z==0) ? W0 : (z==1) ? W1 : (z==2) ? W2 : W3;
        __bf16*      T = (z==0) ? T0 : (z==1) ? T1 : (z==2) ? T2 : T3;
        const float s = (z == 0) ? SSCALE : 1.0f;
        const int kb = blockIdx.x * 32, nb = blockIdx.y * 32;
        const int c = threadIdx.x & 31, r0 = threadIdx.x >> 5;
#pragma unroll
        for (int i = 0; i < 4; ++i)
            tile[r0 + 8*i][c] = W[(size_t)(kb + r0 + 8*i)*1024 + nb + c];
        __syncthreads();
#pragma unroll
        for (int i = 0; i < 4; ++i)
            T[(size_t)(nb + r0 + 8*i)*1024 + kb + c] = (__bf16)(tile[c][r0 + 8*i] * s);
    } else {
        const float* X = (z==4) ? X0 : (z==5) ? X1 : X2;
        __bf16*      Y = (z==4) ? Y0 : (z==5) ? Y1 : Y2;
        const size_t base =
            ((size_t)(blockIdx.y * 32 + blockIdx.x) * 256 + threadIdx.x) * 16;
#pragma unroll
        for (int j = 0; j < 2; ++j) {
            const float4* s4 = (const float4*)(X + base + j*8);
            float4 f0 = s4[0], f1 = s4[1];
            bf16x8 v;
            v[0]=(__bf16)f0.x; v[1]=(__bf16)f0.y; v[2]=(__bf16)f0.z; v[3]=(__bf16)f0.w;
            v[4]=(__bf16)f1.x; v[5]=(__bf16)f1.y; v[6]=(__bf16)f1.z; v[7]=(__bf16)f1.w;
            *(bf16x8*)(Y + base + j*8) = v;
        }
    }
}

// ---------------------------------------------------------------------------
// 128x128 tile GEMM for QKV projections (m97 structure + XOR swizzle).
// mode 0: C bf16 [nh][t][64]   (q / k); bias scaled by bscale
// mode 1: C bf16 [nh][64][t]   (vT, t-PERMUTED: group-index low-2-bit swap)
// ---------------------------------------------------------------------------
struct GArg { const __bf16* A; const __bf16* Bt; const float* bias; void* C;
              int mode; int kbase; int kcount; float bscale; };
struct GArgs3 { GArg a[3]; };

__global__ __launch_bounds__(256)
void gemmk(GArgs3 args)
{
    const GArg g = args.a[blockIdx.z];
    __shared__ __attribute__((aligned(16))) __bf16 As[128*64];
    __shared__ __attribute__((aligned(16))) __bf16 Bs[128*64];
    const int tid = threadIdx.x, lane = tid & 63, wave = tid >> 6;
    const int wm = wave >> 1, wn = wave & 1;
    const int quad = lane >> 4, l16 = lane & 15;
    const int bm = blockIdx.x, bn = blockIdx.y;

    f32x4 acc[4][4] = {};

    for (int kt = 0; kt < g.kcount; ++kt) {
        const int k0 = g.kbase + kt*64;
        __syncthreads();
#pragma unroll
        for (int j = 0; j < 4; ++j) {
            const int ci = j*256 + tid;
            const int row = ci >> 3, cg = ((ci & 7) ^ (row & 7)) * 8;
            glds16(g.A + (size_t)(bm*128 + row)*1024 + k0 + cg,
                   &As[(j*256 + wave*64)*8]);
        }
#pragma unroll
        for (int j = 0; j < 4; ++j) {
            const int ci = j*256 + tid;
            const int row = ci >> 3, cg = ((ci & 7) ^ (row & 7)) * 8;
            glds16(g.Bt + (size_t)(bn*128 + row)*1024 + k0 + cg,
                   &Bs[(j*256 + wave*64)*8]);
        }
        __syncthreads();
#pragma unroll
        for (int ks = 0; ks < 2; ++ks) {
            const int kc = ks*4 + quad;
            bf16x8 af[4], bfr[4];
#pragma unroll
            for (int mt = 0; mt < 4; ++mt) {
                const int ar = wm*64 + mt*16 + l16;
                af[mt] = *(const bf16x8*)&As[ar*64 + (kc ^ (ar & 7))*8];
            }
#pragma unroll
            for (int nt = 0; nt < 4; ++nt) {
                const int br = wn*64 + nt*16 + l16;
                bfr[nt] = *(const bf16x8*)&Bs[br*64 + (kc ^ (br & 7))*8];
            }
#pragma unroll
            for (int mt = 0; mt < 4; ++mt)
#pragma unroll
                for (int nt = 0; nt < 4; ++nt)
                    acc[mt][nt] = MFMA16(af[mt], bfr[nt], acc[mt][nt]);
        }
    }

    // Epilogue. C-layout: col = l16, rows = quad*4 + r.
#pragma unroll
    for (int nt = 0; nt < 4; ++nt) {
        const int n = bn*128 + wn*64 + nt*16 + l16;
        const float bvs = (g.bias ? g.bias[n] : 0.f) * g.bscale;
#pragma unroll
        for (int mt = 0; mt < 4; ++mt) {
            const int mbase = bm*128 + wm*64 + mt*16 + quad*4;
            f32x4 v = acc[mt][nt];
            if (g.mode == 0) {
                __bf16* C = (__bf16*)g.C;
                const int h = n >> 6, d = n & 63;
#pragma unroll
                for (int r = 0; r < 4; ++r) {
                    const int m = mbase + r;
                    const int nb = m >> 11, s = m & 2047;
                    C[(size_t)(nb*NHEAD + h)*(SEQ*HD) + (size_t)s*HD + d] = (__bf16)(v[r] + bvs);
                }
            } else {
                __bf16* C = (__bf16*)g.C;
                const int h = n >> 6, d = n & 63;
                const int nb = mbase >> 11, s = mbase & 2047;
                // t-permute: within each 32-block, swap low 2 bits of the
                // 4-group index (tg 1<->2, 5<->6).
                const int tg = (s >> 2) & 7;
                const int pg = (tg & 4) | ((tg & 1) << 1) | ((tg & 2) >> 1);
                const int sp = (s & ~31) | (pg << 2);
                bf16x4 o;
#pragma unroll
                for (int r = 0; r < 4; ++r) o[r] = (__bf16)(v[r] + bvs);
                *(bf16x4*)&C[(size_t)(nb*NHEAD + h)*(SEQ*HD) + (size_t)d*SEQ + sp] = o;
            }
        }
    }
}

// ---------------------------------------------------------------------------
// Out-projection GEMM: 64x128 tiles (512 blocks -> 3 blocks/CU by LDS),
// C fp32 plain store + bias. A bf16 [4096][1024], Bt = WoT.
// ---------------------------------------------------------------------------
__global__ __launch_bounds__(256)
void gemmo(const __bf16* __restrict__ A, const __bf16* __restrict__ Bt,
           const float* __restrict__ bias, float* __restrict__ C)
{
    __shared__ __attribute__((aligned(16))) __bf16 As[64*64];
    __shared__ __attribute__((aligned(16))) __bf16 Bs[128*64];
    const int tid = threadIdx.x, lane = tid & 63, wave = tid >> 6;  // wave = n-strip
    const int quad = lane >> 4, l16 = lane & 15;
    const int bm = blockIdx.x, bn = blockIdx.y;

    f32x4 acc[4][2] = {};

    for (int k0 = 0; k0 < 1024; k0 += 64) {
        __syncthreads();
#pragma unroll
        for (int j = 0; j < 2; ++j) {
            const int ci = j*256 + tid;
            const int row = ci >> 3, cg = ((ci & 7) ^ (row & 7)) * 8;
            glds16(A + (size_t)(bm*64 + row)*1024 + k0 + cg,
                   &As[(j*256 + wave*64)*8]);
        }
#pragma unroll
        for (int j = 0; j < 4; ++j) {
            const int ci = j*256 + tid;
            const int row = ci >> 3, cg = ((ci & 7) ^ (row & 7)) * 8;
            glds16(Bt + (size_t)(bn*128 + row)*1024 + k0 + cg,
                   &Bs[(j*256 + wave*64)*8]);
        }
        __syncthreads();
#pragma unroll
        for (int ks = 0; ks < 2; ++ks) {
            const int kc = ks*4 + quad;
            bf16x8 af[4], bfr[2];
#pragma unroll
            for (int mt = 0; mt < 4; ++mt) {
                const int ar = mt*16 + l16;
                af[mt] = *(const bf16x8*)&As[ar*64 + (kc ^ (ar & 7))*8];
            }
#pragma unroll
            for (int nt = 0; nt < 2; ++nt) {
                const int br = wave*32 + nt*16 + l16;
                bfr[nt] = *(const bf16x8*)&Bs[br*64 + (kc ^ (br & 7))*8];
            }
#pragma unroll
            for (int mt = 0; mt < 4; ++mt)
#pragma unroll
                for (int nt = 0; nt < 2; ++nt)
                    acc[mt][nt] = MFMA16(af[mt], bfr[nt], acc[mt][nt]);
        }
    }
#pragma unroll
    for (int nt = 0; nt < 2; ++nt) {
        const int n = bn*128 + wave*32 + nt*16 + l16;
        const float bv = bias[n];
#pragma unroll
        for (int mt = 0; mt < 4; ++mt) {
            const int mbase = bm*64 + mt*16 + quad*4;
            f32x4 v = acc[mt][nt];
#pragma unroll
            for (int r = 0; r < 4; ++r)
                C[(size_t)(mbase + r)*1024 + n] = v[r] + bv;
        }
    }
}

// ---------------------------------------------------------------------------
// Flash attention, 32x32x16 MFMA, register P, 8 waves (512 thr).
// Wave group g = wave>>2 handles t-half g of each staged 256-t tile; both
// groups cover the same 128 Q-rows (w4 = wave&3, 32 rows each). Fixed-shift
// softmax => group partials (oacc, osum) combine by plain addition via LDS.
// q,k: [nh][t][64]; vT: [nh][64][t-permuted]; O: [N,S,E] bf16.
// ---------------------------------------------------------------------------
__global__ __launch_bounds__(512, 4)
void attn32(const __bf16* __restrict__ qg, const __bf16* __restrict__ kg,
            const __bf16* __restrict__ vg, __bf16* __restrict__ Og)
{
    __shared__ __attribute__((aligned(16))) char smem[64*1024];
    __bf16* Ks = (__bf16*)smem;              // [256][64] swizzled (32 KB)
    __bf16* Vs = (__bf16*)(smem + 32768);    // [64][256] swizzled (32 KB)
    float*  Xch = (float*)smem;              // combine area [4][64][48] (48 KB)

    const int tid = threadIdx.x, lane = tid & 63, wave = tid >> 6;
    const int w4 = wave & 3, grp = wave >> 2;
    const int l32 = lane & 31, half = lane >> 5;
    const int nh = blockIdx.y;
    const int q0 = blockIdx.x * 128;
    const __bf16* qb = qg + (size_t)nh * (SEQ*HD);
    const __bf16* kb = kg + (size_t)nh * (SEQ*HD);
    const __bf16* vb = vg + (size_t)nh * (SEQ*HD);

    // Q B-frags from global, loop-invariant: B[k=ks*16+half*8+j][n=l32]
    bf16x8 qf[4];
#pragma unroll
    for (int ks = 0; ks < 4; ++ks)
        qf[ks] = *(const bf16x8*)(qb + (size_t)(q0 + w4*32 + l32)*HD + ks*16 + half*8);

    bf16x8 vone;
#pragma unroll
    for (int i = 0; i < 8; ++i) vone[i] = (__bf16)1.0f;

    f32x16 oacc[2] = {};
    f32x16 osum = {};

    for (int t0 = 0; t0 < SEQ; t0 += 256) {
        __syncthreads();
#pragma unroll
        for (int j = 0; j < 4; ++j) {   // stage K 256x64 (swizzled)
            const int ci = j*512 + tid;
            const int row = ci >> 3, cg = ((ci & 7) ^ (row & 7)) * 8;
            glds16(kb + (size_t)(t0 + row)*HD + cg, &Ks[(j*512 + wave*64)*8]);
        }
#pragma unroll
        for (int j = 0; j < 4; ++j) {   // stage vT 64x256 (swizzled)
            const int ci = j*512 + tid;
            const int row = ci >> 5, pos = ci & 31;
            const int cg = ((pos & ~7) | ((pos & 7) ^ (row & 7))) * 8;
            glds16(vb + (size_t)row*SEQ + t0 + cg, &Vs[(j*512 + wave*64)*8]);
        }
        __syncthreads();

        // S^T = K Q^T on this group's 128-t half: lane = m, regs = t.
        f32x16 sc[4] = {};
#pragma unroll
        for (int ks = 0; ks < 4; ++ks) {
            const int c = ks*2 + half;
#pragma unroll
            for (int nt = 0; nt < 4; ++nt) {
                const int kr = grp*128 + nt*32 + l32;
                bf16x8 kf = *(const bf16x8*)&Ks[kr*64 + ((c ^ (kr & 7))*8)];
                sc[nt] = MFMA32(kf, qf[ks], sc[nt]);
            }
        }

        // P = exp2(S^T) in-register -> PV A-frags; O += P V; osum += P * 1.
#pragma unroll
        for (int nt = 0; nt < 4; ++nt)
#pragma unroll
            for (int sub = 0; sub < 2; ++sub) {
                bf16x8 pf;
#pragma unroll
                for (int j = 0; j < 8; ++j)
                    pf[j] = (__bf16)exp2f(sc[nt][sub*8 + j]);
                const int c2 = grp*16 + (nt*2 + sub)*2 + half;
#pragma unroll
                for (int dt = 0; dt < 2; ++dt) {
                    const int vr = dt*32 + l32;
                    const int pos = (c2 & ~7) | ((c2 & 7) ^ (vr & 7));
                    bf16x8 vf = *(const bf16x8*)&Vs[vr*256 + pos*8];
                    oacc[dt] = MFMA32(pf, vf, oacc[dt]);
                }
                osum = MFMA32(pf, vone, osum);
            }
    }

    // Combine group partials: group 1 publishes, group 0 adds + writes out.
    __syncthreads();
    if (grp == 1) {
        float* dst = &Xch[((w4*64) + lane) * 48];
#pragma unroll
        for (int i = 0; i < 16; ++i) {
            dst[i]      = oacc[0][i];
            dst[16 + i] = oacc[1][i];
            dst[32 + i] = osum[i];
        }
    }
    __syncthreads();
    if (grp == 0) {
        const float* src = &Xch[((w4*64) + lane) * 48];
#pragma unroll
        for (int i = 0; i < 16; ++i) {
            oacc[0][i] += src[i];
            oacc[1][i] += src[16 + i];
            osum[i]    += src[32 + i];
        }
        const int nb = nh >> 4, h = nh & 15;
#pragma unroll
        for (int reg = 0; reg < 16; ++reg) {
            const int row = (reg & 3) + 8*(reg >> 2) + 4*half;
            const int srow = q0 + w4*32 + row;
            const float inv = 1.0f / osum[reg];
#pragma unroll
            for (int dt = 0; dt < 2; ++dt)
                Og[(size_t)(nb*SEQ + srow)*EMB + h*HD + dt*32 + l32] =
                    (__bf16)(oacc[dt][reg] * inv);
        }
    }
}

// ---------------------------------------------------------------------------
extern "C" void kernel_launch(void* const* d_in, const int* in_sizes, int n_in,
                              void* d_out, int out_size, void* d_ws, size_t ws_size,
                              hipStream_t stream)
{
    const float* query = (const float*)d_in[0];
    const float* key_  = (const float*)d_in[1];
    const float* value = (const float*)d_in[2];
    const float* Wq = (const float*)d_in[3];
    const float* bq = (const float*)d_in[4];
    const float* Wk = (const float*)d_in[5];
    const float* bk = (const float*)d_in[6];
    const float* Wv = (const float*)d_in[7];
    const float* bv = (const float*)d_in[8];
    const float* Wo = (const float*)d_in[9];
    const float* bo = (const float*)d_in[10];
    float* out = (float*)d_out;

    // d_out (16 MB) doubles as scratch for xq/xk until the out-projection.
    constexpr size_t SZW = 1024u*1024u;   // one weight matrix (elements)
    constexpr size_t SZX = 4096u*1024u;   // one activation tensor (elements)
    __bf16* ws  = (__bf16*)d_ws;
    __bf16* WqT = ws;
    __bf16* WkT = WqT + SZW;
    __bf16* WvT = WkT + SZW;
    __bf16* WoT = WvT + SZW;
    __bf16* xv  = WoT + SZW;
    __bf16* qh  = xv + SZX;
    __bf16* kh  = qh + SZX;
    __bf16* vTh = kh + SZX;              // ws total: 40 MiB
    __bf16* xq  = (__bf16*)d_out;        // first 8 MB of d_out
    __bf16* xk  = xq + SZX;              // second 8 MB of d_out
    __bf16* Oh  = xv;                    // xv dead after QKV GEMM

    // 1) weight transpose/cast (+Wq pre-scale) and activation fp32->bf16
    prep<<<dim3(32, 32, 7), 256, 0, stream>>>(Wq, Wk, Wv, Wo, WqT, WkT, WvT, WoT,
                                              query, key_, value, xq, xk, xv);
    // 2) fused QKV projections (single dispatch, 768 blocks)
    GArgs3 a;
    a.a[0] = { xq, WqT, bq, qh,  0, 0, 16, SSCALE };
    a.a[1] = { xk, WkT, bk, kh,  0, 0, 16, 1.0f };
    a.a[2] = { xv, WvT, bv, vTh, 1, 0, 16, 1.0f };
    gemmk<<<dim3(32, 8, 3), 256, 0, stream>>>(a);
    // 3) flash attention (32x32 MFMA, register P, 8-wave T-split blocks)
    attn32<<<dim3(16, 32), 512, 0, stream>>>(qh, kh, vTh, Oh);
    // 4) out-projection: 64x128 tiles, 512 blocks, plain fp32 stores
    gemmo<<<dim3(64, 8), 256, 0, stream>>>(Oh, WoT, bo, out);
}

// Round 8
// 238.680 us; speedup vs baseline: 1.1425x; 1.1425x over previous
//
#include <hip/hip_runtime.h>
#include <hip/hip_bf16.h>

// MHA forward: N=2, S=T=2048, E=1024, H=16, HD=64. All-bf16 MFMA pipeline.
// attn: 32x32x16 MFMA, S^T trick (P in registers), 8-wave blocks with T-split
// wave groups + exact partial combine (fixed-shift softmax => sums add).
// vT stored t-permuted so register P is directly a PV A-operand.
// LDS XOR-chunk swizzle: slot (row,p) holds chunk p ^ (row&7).
// NOTE: launch_bounds (512,2) NOT (512,4) — the latter caps VGPR at 64 and
// spills ~140 MB/launch to scratch (round-7 regression: WRITE_SIZE 144 MB).
typedef __bf16 bf16x8 __attribute__((ext_vector_type(8)));
typedef __bf16 bf16x4 __attribute__((ext_vector_type(4)));
typedef float  f32x4  __attribute__((ext_vector_type(4)));
typedef float  f32x16 __attribute__((ext_vector_type(16)));

#define MFMA16(a, b, c) __builtin_amdgcn_mfma_f32_16x16x32_bf16((a), (b), (c), 0, 0, 0)
#define MFMA32(a, b, c) __builtin_amdgcn_mfma_f32_32x32x16_bf16((a), (b), (c), 0, 0, 0)

constexpr int SEQ = 2048, EMB = 1024, NHEAD = 16, HD = 64;
constexpr float SSCALE = 0.18033688f;  // (1/8) * log2(e)

__device__ __forceinline__ void glds16(const void* g, void* l) {
    __builtin_amdgcn_global_load_lds(
        (const __attribute__((address_space(1))) void*)g,
        (__attribute__((address_space(3))) void*)l, 16, 0, 0);
}

// ---------------------------------------------------------------------------
// prep: z<4 -> weight transpose+cast (z==0 pre-scaled by SSCALE);
//       z>=4 -> fp32->bf16 convert of query/key/value.
// ---------------------------------------------------------------------------
__global__ __launch_bounds__(256)
void prep(const float* __restrict__ W0, const float* __restrict__ W1,
          const float* __restrict__ W2, const float* __restrict__ W3,
          __bf16* __restrict__ T0, __bf16* __restrict__ T1,
          __bf16* __restrict__ T2, __bf16* __restrict__ T3,
          const float* __restrict__ X0, const float* __restrict__ X1,
          const float* __restrict__ X2, __bf16* __restrict__ Y0,
          __bf16* __restrict__ Y1, __bf16* __restrict__ Y2)
{
    __shared__ float tile[32][33];
    const int z = blockIdx.z;
    if (z < 4) {
        const float* W = (z==0) ? W0 : (z==1) ? W1 : (z==2) ? W2 : W3;
        __bf16*      T = (z==0) ? T0 : (z==1) ? T1 : (z==2) ? T2 : T3;
        const float s = (z == 0) ? SSCALE : 1.0f;
        const int kb = blockIdx.x * 32, nb = blockIdx.y * 32;
        const int c = threadIdx.x & 31, r0 = threadIdx.x >> 5;
#pragma unroll
        for (int i = 0; i < 4; ++i)
            tile[r0 + 8*i][c] = W[(size_t)(kb + r0 + 8*i)*1024 + nb + c];
        __syncthreads();
#pragma unroll
        for (int i = 0; i < 4; ++i)
            T[(size_t)(nb + r0 + 8*i)*1024 + kb + c] = (__bf16)(tile[c][r0 + 8*i] * s);
    } else {
        const float* X = (z==4) ? X0 : (z==5) ? X1 : X2;
        __bf16*      Y = (z==4) ? Y0 : (z==5) ? Y1 : Y2;
        const size_t base =
            ((size_t)(blockIdx.y * 32 + blockIdx.x) * 256 + threadIdx.x) * 16;
#pragma unroll
        for (int j = 0; j < 2; ++j) {
            const float4* s4 = (const float4*)(X + base + j*8);
            float4 f0 = s4[0], f1 = s4[1];
            bf16x8 v;
            v[0]=(__bf16)f0.x; v[1]=(__bf16)f0.y; v[2]=(__bf16)f0.z; v[3]=(__bf16)f0.w;
            v[4]=(__bf16)f1.x; v[5]=(__bf16)f1.y; v[6]=(__bf16)f1.z; v[7]=(__bf16)f1.w;
            *(bf16x8*)(Y + base + j*8) = v;
        }
    }
}

// ---------------------------------------------------------------------------
// 128x128 tile GEMM for QKV projections (m97 structure + XOR swizzle).
// mode 0: C bf16 [nh][t][64]   (q / k); bias scaled by bscale
// mode 1: C bf16 [nh][64][t]   (vT, t-PERMUTED: group-index low-2-bit swap)
// ---------------------------------------------------------------------------
struct GArg { const __bf16* A; const __bf16* Bt; const float* bias; void* C;
              int mode; int kbase; int kcount; float bscale; };
struct GArgs3 { GArg a[3]; };

__global__ __launch_bounds__(256)
void gemmk(GArgs3 args)
{
    const GArg g = args.a[blockIdx.z];
    __shared__ __attribute__((aligned(16))) __bf16 As[128*64];
    __shared__ __attribute__((aligned(16))) __bf16 Bs[128*64];
    const int tid = threadIdx.x, lane = tid & 63, wave = tid >> 6;
    const int wm = wave >> 1, wn = wave & 1;
    const int quad = lane >> 4, l16 = lane & 15;
    const int bm = blockIdx.x, bn = blockIdx.y;

    f32x4 acc[4][4] = {};

    for (int kt = 0; kt < g.kcount; ++kt) {
        const int k0 = g.kbase + kt*64;
        __syncthreads();
#pragma unroll
        for (int j = 0; j < 4; ++j) {
            const int ci = j*256 + tid;
            const int row = ci >> 3, cg = ((ci & 7) ^ (row & 7)) * 8;
            glds16(g.A + (size_t)(bm*128 + row)*1024 + k0 + cg,
                   &As[(j*256 + wave*64)*8]);
        }
#pragma unroll
        for (int j = 0; j < 4; ++j) {
            const int ci = j*256 + tid;
            const int row = ci >> 3, cg = ((ci & 7) ^ (row & 7)) * 8;
            glds16(g.Bt + (size_t)(bn*128 + row)*1024 + k0 + cg,
                   &Bs[(j*256 + wave*64)*8]);
        }
        __syncthreads();
#pragma unroll
        for (int ks = 0; ks < 2; ++ks) {
            const int kc = ks*4 + quad;
            bf16x8 af[4], bfr[4];
#pragma unroll
            for (int mt = 0; mt < 4; ++mt) {
                const int ar = wm*64 + mt*16 + l16;
                af[mt] = *(const bf16x8*)&As[ar*64 + (kc ^ (ar & 7))*8];
            }
#pragma unroll
            for (int nt = 0; nt < 4; ++nt) {
                const int br = wn*64 + nt*16 + l16;
                bfr[nt] = *(const bf16x8*)&Bs[br*64 + (kc ^ (br & 7))*8];
            }
#pragma unroll
            for (int mt = 0; mt < 4; ++mt)
#pragma unroll
                for (int nt = 0; nt < 4; ++nt)
                    acc[mt][nt] = MFMA16(af[mt], bfr[nt], acc[mt][nt]);
        }
    }

    // Epilogue. C-layout: col = l16, rows = quad*4 + r.
#pragma unroll
    for (int nt = 0; nt < 4; ++nt) {
        const int n = bn*128 + wn*64 + nt*16 + l16;
        const float bvs = (g.bias ? g.bias[n] : 0.f) * g.bscale;
#pragma unroll
        for (int mt = 0; mt < 4; ++mt) {
            const int mbase = bm*128 + wm*64 + mt*16 + quad*4;
            f32x4 v = acc[mt][nt];
            if (g.mode == 0) {
                __bf16* C = (__bf16*)g.C;
                const int h = n >> 6, d = n & 63;
#pragma unroll
                for (int r = 0; r < 4; ++r) {
                    const int m = mbase + r;
                    const int nb = m >> 11, s = m & 2047;
                    C[(size_t)(nb*NHEAD + h)*(SEQ*HD) + (size_t)s*HD + d] = (__bf16)(v[r] + bvs);
                }
            } else {
                __bf16* C = (__bf16*)g.C;
                const int h = n >> 6, d = n & 63;
                const int nb = mbase >> 11, s = mbase & 2047;
                // t-permute: within each 32-block, swap low 2 bits of the
                // 4-group index (tg 1<->2, 5<->6).
                const int tg = (s >> 2) & 7;
                const int pg = (tg & 4) | ((tg & 1) << 1) | ((tg & 2) >> 1);
                const int sp = (s & ~31) | (pg << 2);
                bf16x4 o;
#pragma unroll
                for (int r = 0; r < 4; ++r) o[r] = (__bf16)(v[r] + bvs);
                *(bf16x4*)&C[(size_t)(nb*NHEAD + h)*(SEQ*HD) + (size_t)d*SEQ + sp] = o;
            }
        }
    }
}

// ---------------------------------------------------------------------------
// Out-projection GEMM: 64x128 tiles (512 blocks -> 3 blocks/CU by LDS),
// C fp32 plain store + bias. A bf16 [4096][1024], Bt = WoT.
// ---------------------------------------------------------------------------
__global__ __launch_bounds__(256)
void gemmo(const __bf16* __restrict__ A, const __bf16* __restrict__ Bt,
           const float* __restrict__ bias, float* __restrict__ C)
{
    __shared__ __attribute__((aligned(16))) __bf16 As[64*64];
    __shared__ __attribute__((aligned(16))) __bf16 Bs[128*64];
    const int tid = threadIdx.x, lane = tid & 63, wave = tid >> 6;  // wave = n-strip
    const int quad = lane >> 4, l16 = lane & 15;
    const int bm = blockIdx.x, bn = blockIdx.y;

    f32x4 acc[4][2] = {};

    for (int k0 = 0; k0 < 1024; k0 += 64) {
        __syncthreads();
#pragma unroll
        for (int j = 0; j < 2; ++j) {
            const int ci = j*256 + tid;
            const int row = ci >> 3, cg = ((ci & 7) ^ (row & 7)) * 8;
            glds16(A + (size_t)(bm*64 + row)*1024 + k0 + cg,
                   &As[(j*256 + wave*64)*8]);
        }
#pragma unroll
        for (int j = 0; j < 4; ++j) {
            const int ci = j*256 + tid;
            const int row = ci >> 3, cg = ((ci & 7) ^ (row & 7)) * 8;
            glds16(Bt + (size_t)(bn*128 + row)*1024 + k0 + cg,
                   &Bs[(j*256 + wave*64)*8]);
        }
        __syncthreads();
#pragma unroll
        for (int ks = 0; ks < 2; ++ks) {
            const int kc = ks*4 + quad;
            bf16x8 af[4], bfr[2];
#pragma unroll
            for (int mt = 0; mt < 4; ++mt) {
                const int ar = mt*16 + l16;
                af[mt] = *(const bf16x8*)&As[ar*64 + (kc ^ (ar & 7))*8];
            }
#pragma unroll
            for (int nt = 0; nt < 2; ++nt) {
                const int br = wave*32 + nt*16 + l16;
                bfr[nt] = *(const bf16x8*)&Bs[br*64 + (kc ^ (br & 7))*8];
            }
#pragma unroll
            for (int mt = 0; mt < 4; ++mt)
#pragma unroll
                for (int nt = 0; nt < 2; ++nt)
                    acc[mt][nt] = MFMA16(af[mt], bfr[nt], acc[mt][nt]);
        }
    }
#pragma unroll
    for (int nt = 0; nt < 2; ++nt) {
        const int n = bn*128 + wave*32 + nt*16 + l16;
        const float bv = bias[n];
#pragma unroll
        for (int mt = 0; mt < 4; ++mt) {
            const int mbase = bm*64 + mt*16 + quad*4;
            f32x4 v = acc[mt][nt];
#pragma unroll
            for (int r = 0; r < 4; ++r)
                C[(size_t)(mbase + r)*1024 + n] = v[r] + bv;
        }
    }
}

// ---------------------------------------------------------------------------
// Flash attention, 32x32x16 MFMA, register P, 8 waves (512 thr).
// Wave group g = wave>>2 handles t-half g of each staged 256-t tile; both
// groups cover the same 128 Q-rows (w4 = wave&3, 32 rows each). Fixed-shift
// softmax => group partials (oacc, osum) combine by plain addition via LDS.
// q,k: [nh][t][64]; vT: [nh][64][t-permuted]; O: [N,S,E] bf16.
// ---------------------------------------------------------------------------
__global__ __launch_bounds__(512, 2)
void attn32(const __bf16* __restrict__ qg, const __bf16* __restrict__ kg,
            const __bf16* __restrict__ vg, __bf16* __restrict__ Og)
{
    __shared__ __attribute__((aligned(16))) char smem[64*1024];
    __bf16* Ks = (__bf16*)smem;              // [256][64] swizzled (32 KB)
    __bf16* Vs = (__bf16*)(smem + 32768);    // [64][256] swizzled (32 KB)
    float*  Xch = (float*)smem;              // combine area [4][64][48] (48 KB)

    const int tid = threadIdx.x, lane = tid & 63, wave = tid >> 6;
    const int w4 = wave & 3, grp = wave >> 2;
    const int l32 = lane & 31, half = lane >> 5;
    const int nh = blockIdx.y;
    const int q0 = blockIdx.x * 128;
    const __bf16* qb = qg + (size_t)nh * (SEQ*HD);
    const __bf16* kb = kg + (size_t)nh * (SEQ*HD);
    const __bf16* vb = vg + (size_t)nh * (SEQ*HD);

    // Q B-frags from global, loop-invariant: B[k=ks*16+half*8+j][n=l32]
    bf16x8 qf[4];
#pragma unroll
    for (int ks = 0; ks < 4; ++ks)
        qf[ks] = *(const bf16x8*)(qb + (size_t)(q0 + w4*32 + l32)*HD + ks*16 + half*8);

    bf16x8 vone;
#pragma unroll
    for (int i = 0; i < 8; ++i) vone[i] = (__bf16)1.0f;

    f32x16 oacc[2] = {};
    f32x16 osum = {};

    for (int t0 = 0; t0 < SEQ; t0 += 256) {
        __syncthreads();
#pragma unroll
        for (int j = 0; j < 4; ++j) {   // stage K 256x64 (swizzled)
            const int ci = j*512 + tid;
            const int row = ci >> 3, cg = ((ci & 7) ^ (row & 7)) * 8;
            glds16(kb + (size_t)(t0 + row)*HD + cg, &Ks[(j*512 + wave*64)*8]);
        }
#pragma unroll
        for (int j = 0; j < 4; ++j) {   // stage vT 64x256 (swizzled)
            const int ci = j*512 + tid;
            const int row = ci >> 5, pos = ci & 31;
            const int cg = ((pos & ~7) | ((pos & 7) ^ (row & 7))) * 8;
            glds16(vb + (size_t)row*SEQ + t0 + cg, &Vs[(j*512 + wave*64)*8]);
        }
        __syncthreads();

        // S^T = K Q^T on this group's 128-t half: lane = m, regs = t.
        f32x16 sc[4] = {};
#pragma unroll
        for (int ks = 0; ks < 4; ++ks) {
            const int c = ks*2 + half;
#pragma unroll
            for (int nt = 0; nt < 4; ++nt) {
                const int kr = grp*128 + nt*32 + l32;
                bf16x8 kf = *(const bf16x8*)&Ks[kr*64 + ((c ^ (kr & 7))*8)];
                sc[nt] = MFMA32(kf, qf[ks], sc[nt]);
            }
        }

        // P = exp2(S^T) in-register -> PV A-frags; O += P V; osum += P * 1.
#pragma unroll
        for (int nt = 0; nt < 4; ++nt)
#pragma unroll
            for (int sub = 0; sub < 2; ++sub) {
                bf16x8 pf;
#pragma unroll
                for (int j = 0; j < 8; ++j)
                    pf[j] = (__bf16)exp2f(sc[nt][sub*8 + j]);
                const int c2 = grp*16 + (nt*2 + sub)*2 + half;
#pragma unroll
                for (int dt = 0; dt < 2; ++dt) {
                    const int vr = dt*32 + l32;
                    const int pos = (c2 & ~7) | ((c2 & 7) ^ (vr & 7));
                    bf16x8 vf = *(const bf16x8*)&Vs[vr*256 + pos*8];
                    oacc[dt] = MFMA32(pf, vf, oacc[dt]);
                }
                osum = MFMA32(pf, vone, osum);
            }
    }

    // Combine group partials: group 1 publishes, group 0 adds + writes out.
    __syncthreads();
    if (grp == 1) {
        float* dst = &Xch[((w4*64) + lane) * 48];
#pragma unroll
        for (int i = 0; i < 16; ++i) {
            dst[i]      = oacc[0][i];
            dst[16 + i] = oacc[1][i];
            dst[32 + i] = osum[i];
        }
    }
    __syncthreads();
    if (grp == 0) {
        const float* src = &Xch[((w4*64) + lane) * 48];
#pragma unroll
        for (int i = 0; i < 16; ++i) {
            oacc[0][i] += src[i];
            oacc[1][i] += src[16 + i];
            osum[i]    += src[32 + i];
        }
        const int nb = nh >> 4, h = nh & 15;
#pragma unroll
        for (int reg = 0; reg < 16; ++reg) {
            const int row = (reg & 3) + 8*(reg >> 2) + 4*half;
            const int srow = q0 + w4*32 + row;
            const float inv = 1.0f / osum[reg];
#pragma unroll
            for (int dt = 0; dt < 2; ++dt)
                Og[(size_t)(nb*SEQ + srow)*EMB + h*HD + dt*32 + l32] =
                    (__bf16)(oacc[dt][reg] * inv);
        }
    }
}

// ---------------------------------------------------------------------------
extern "C" void kernel_launch(void* const* d_in, const int* in_sizes, int n_in,
                              void* d_out, int out_size, void* d_ws, size_t ws_size,
                              hipStream_t stream)
{
    const float* query = (const float*)d_in[0];
    const float* key_  = (const float*)d_in[1];
    const float* value = (const float*)d_in[2];
    const float* Wq = (const float*)d_in[3];
    const float* bq = (const float*)d_in[4];
    const float* Wk = (const float*)d_in[5];
    const float* bk = (const float*)d_in[6];
    const float* Wv = (const float*)d_in[7];
    const float* bv = (const float*)d_in[8];
    const float* Wo = (const float*)d_in[9];
    const float* bo = (const float*)d_in[10];
    float* out = (float*)d_out;

    // d_out (16 MB) doubles as scratch for xq/xk until the out-projection.
    constexpr size_t SZW = 1024u*1024u;   // one weight matrix (elements)
    constexpr size_t SZX = 4096u*1024u;   // one activation tensor (elements)
    __bf16* ws  = (__bf16*)d_ws;
    __bf16* WqT = ws;
    __bf16* WkT = WqT + SZW;
    __bf16* WvT = WkT + SZW;
    __bf16* WoT = WvT + SZW;
    __bf16* xv  = WoT + SZW;
    __bf16* qh  = xv + SZX;
    __bf16* kh  = qh + SZX;
    __bf16* vTh = kh + SZX;              // ws total: 40 MiB
    __bf16* xq  = (__bf16*)d_out;        // first 8 MB of d_out
    __bf16* xk  = xq + SZX;              // second 8 MB of d_out
    __bf16* Oh  = xv;                    // xv dead after QKV GEMM

    // 1) weight transpose/cast (+Wq pre-scale) and activation fp32->bf16
    prep<<<dim3(32, 32, 7), 256, 0, stream>>>(Wq, Wk, Wv, Wo, WqT, WkT, WvT, WoT,
                                              query, key_, value, xq, xk, xv);
    // 2) fused QKV projections (single dispatch, 768 blocks)
    GArgs3 a;
    a.a[0] = { xq, WqT, bq, qh,  0, 0, 16, SSCALE };
    a.a[1] = { xk, WkT, bk, kh,  0, 0, 16, 1.0f };
    a.a[2] = { xv, WvT, bv, vTh, 1, 0, 16, 1.0f };
    gemmk<<<dim3(32, 8, 3), 256, 0, stream>>>(a);
    // 3) flash attention (32x32 MFMA, register P, 8-wave T-split blocks)
    attn32<<<dim3(16, 32), 512, 0, stream>>>(qh, kh, vTh, Oh);
    // 4) out-projection: 64x128 tiles, 512 blocks, plain fp32 stores
    gemmo<<<dim3(64, 8), 256, 0, stream>>>(Oh, WoT, bo, out);
}